// Round 7
// baseline (176.182 us; speedup 1.0000x reference)
//
#include <hip/hip_runtime.h>
#include <hip/hip_bf16.h>
#include <stdint.h>

typedef _Float16 half8 __attribute__((ext_vector_type(8)));
typedef float    f32x4 __attribute__((ext_vector_type(4)));

#define N_EMBED   2048
#define N_EXP     64
#define KCHUNK    64
#define NKC       (N_EMBED / KCHUNK)   // 32
#define GCH       16                   // chunks per K-group (K-split 2)
#define NPAIR     8                    // BK=128 rounds per group
#define TILEB     8192                 // bytes per k-chunk fp16 image
#define LGT_STRIDE 68                  // floats, padded row stride for logit LDS
#define LGT_FLOATS (64 * LGT_STRIDE)   // 4352 floats = 17408 B per region

// ---------------------------------------------------------------------------
// Prelude: W [64][2048] fp32 -> pre-swizzled fp16 image in ws (256 KB).
// Folds the 0.5 = (alpha-1)/temperature scale into W.
// Chunk kc at kc*8192; element (e,dd) at byte ((e*128 + dd*2) ^ ((e&7)<<4)).
// ---------------------------------------------------------------------------
__global__ __launch_bounds__(256) void convert_w_kernel(
        const float* __restrict__ W, uint8_t* __restrict__ wsimg) {
    int tid = blockIdx.x * 256 + threadIdx.x;   // 16384 threads total
    int e   = tid >> 8;                          // expert 0..63
    int d0  = (tid & 255) * 8;                   // 8 consecutive d
    int kc  = d0 >> 6;
    int dd0 = d0 & 63;
    const float* src = W + e * N_EMBED + d0;
    float4 f0 = *(const float4*)(src);
    float4 f1 = *(const float4*)(src + 4);
    float v[8] = {f0.x, f0.y, f0.z, f0.w, f1.x, f1.y, f1.z, f1.w};
    union { _Float16 h[8]; uint4 u; } hv;
#pragma unroll
    for (int j = 0; j < 8; ++j) hv.h[j] = (_Float16)(0.5f * v[j]);
    uint32_t off = (uint32_t)((e * 128 + dd0 * 2) ^ ((e & 7) << 4));
    *(uint4*)(wsimg + (size_t)kc * TILEB + off) = hv.u;
}

// ---------------------------------------------------------------------------
// Main fused kernel, K-split 2, fp16 MFMA, BK=128 (2 chunks per barrier
// round -> 8 rounds instead of 16; halves the per-round convoy cost):
//   512 threads = 8 waves = 2 K-groups x 4 row-quads.
//   W: ring-4 LDS (pair double-buffer of 2 x 8 KB halves per group); stage
//   pair p+1 at round-p start (1-round cover). A: 2 register sets, consume-
//   then-reload pair p+2 (2-round cover). Steady wait vmcnt(8); s_barrier.
// ---------------------------------------------------------------------------
__device__ __forceinline__ half8 cvt8(const float4& p, const float4& q) {
    half8 h;
    h[0] = (_Float16)p.x; h[1] = (_Float16)p.y;
    h[2] = (_Float16)p.z; h[3] = (_Float16)p.w;
    h[4] = (_Float16)q.x; h[5] = (_Float16)q.y;
    h[6] = (_Float16)q.z; h[7] = (_Float16)q.w;
    return h;
}

__global__ __launch_bounds__(512, 4) void router_kernel(
        const float* __restrict__ x, const uint8_t* __restrict__ img,
        const float* __restrict__ bias, float* __restrict__ out) {
    __shared__ uint8_t lds[65536];   // 2 groups x 4 slots x 8 KB; logits overlay

    const int tid  = threadIdx.x;
    const int wave = tid >> 6;
    const int lane = tid & 63;
    const int l15  = lane & 15;
    const int l4   = lane >> 4;
    const int g    = wave >> 2;        // K-group
    const int q    = wave & 3;         // row quad
    const int rowbase = blockIdx.x * 64;
    const float* xrow = x + (size_t)(rowbase + q * 16 + l15) * N_EMBED
                          + g * (GCH * KCHUNK) + l4 * 8;
    uint8_t* gring = lds + g * (4 * TILEB);

    // LDS byte offsets of B fragments: tile t, k-step s
    uint32_t boff[4][2];
#pragma unroll
    for (int t = 0; t < 4; ++t)
#pragma unroll
        for (int s = 0; s < 2; ++s)
            boff[t][s] = (uint32_t)(((16 * t + l15) * 128 + s * 64 + l4 * 16)
                                    ^ ((l15 & 7) << 4));

    f32x4 acc[4];
#pragma unroll
    for (int t = 0; t < 4; ++t) acc[t] = (f32x4){0.f, 0.f, 0.f, 0.f};

    // Staging: thread-group tg (256 threads) stages its group's chunks.
    const int tg  = tid >> 8;
    const int t8  = tid & 255;
    auto STAGE2 = [&](int p) {   // stage chunks 2p, 2p+1 (4 gload_lds/thread)
#pragma unroll
        for (int c = 0; c < 2; ++c) {
            int kc = 2 * p + c;
            const uint8_t* gsrc = img + (size_t)(tg * GCH + kc) * TILEB;
            uint8_t* dst = lds + tg * (4 * TILEB) + (kc & 3) * TILEB;
#pragma unroll
            for (int j = 0; j < 2; ++j) {
                __builtin_amdgcn_global_load_lds(
                    (const __attribute__((address_space(1))) void*)(gsrc + j * 4096 + t8 * 16),
                    (__attribute__((address_space(3))) void*)(dst + j * 4096 + t8 * 16),
                    16, 0, 0);
            }
        }
    };
    auto LOADA2 = [&](int p, float4 A[8]) {   // pair p: 8 x dwordx4
        const float* ap = xrow + 2 * p * KCHUNK;
        A[0] = *(const float4*)(ap);
        A[1] = *(const float4*)(ap + 4);
        A[2] = *(const float4*)(ap + 32);
        A[3] = *(const float4*)(ap + 36);
        A[4] = *(const float4*)(ap + 64);
        A[5] = *(const float4*)(ap + 68);
        A[6] = *(const float4*)(ap + 96);
        A[7] = *(const float4*)(ap + 100);
    };
    auto MFMAS2 = [&](int p, const half8 a[4]) {   // both chunks of pair p
#pragma unroll
        for (int c = 0; c < 2; ++c) {
            const uint8_t* lb = gring + (size_t)((2 * p + c) & 3) * TILEB;
#pragma unroll
            for (int s = 0; s < 2; ++s) {
                half8 ah = a[2 * c + s];
#pragma unroll
                for (int t = 0; t < 4; ++t) {
                    half8 bh = *(const half8*)(lb + boff[t][s]);
                    acc[t] = __builtin_amdgcn_mfma_f32_16x16x32_f16(ah, bh, acc[t], 0, 0, 0);
                }
            }
        }
    };

    float4 Aa[8], Ab[8];

    // ---- prologue: stage pair 0; load A pairs 0,1 ----
    STAGE2(0);
    __builtin_amdgcn_sched_barrier(0);
    LOADA2(0, Aa);
    LOADA2(1, Ab);
    __builtin_amdgcn_sched_barrier(0);
    asm volatile("s_waitcnt vmcnt(16)" ::: "memory");   // S(0) done; A0,A1 in flight
    __builtin_amdgcn_s_barrier();
    __builtin_amdgcn_sched_barrier(0);

    // ---- rounds 0..5 (steady state), parity-unrolled by 2 ----
#pragma unroll 1
    for (int p = 0; p < 6; p += 2) {
        // round p (even, set Aa)
        STAGE2(p + 1);
        __builtin_amdgcn_sched_barrier(0);
        {
            half8 a[4];
            a[0] = cvt8(Aa[0], Aa[1]); a[1] = cvt8(Aa[2], Aa[3]);
            a[2] = cvt8(Aa[4], Aa[5]); a[3] = cvt8(Aa[6], Aa[7]);
            LOADA2(p + 2, Aa);          // reuse set after consume: 2-round cover
            MFMAS2(p, a);
        }
        asm volatile("s_waitcnt vmcnt(8) lgkmcnt(0)" ::: "memory"); // S(p+1),A(p+1) done
        __builtin_amdgcn_s_barrier();
        __builtin_amdgcn_sched_barrier(0);

        // round p+1 (odd, set Ab)
        STAGE2(p + 2);
        __builtin_amdgcn_sched_barrier(0);
        {
            half8 a[4];
            a[0] = cvt8(Ab[0], Ab[1]); a[1] = cvt8(Ab[2], Ab[3]);
            a[2] = cvt8(Ab[4], Ab[5]); a[3] = cvt8(Ab[6], Ab[7]);
            LOADA2(p + 3, Ab);
            MFMAS2(p + 1, a);
        }
        asm volatile("s_waitcnt vmcnt(8) lgkmcnt(0)" ::: "memory"); // S(p+2),A(p+2) done
        __builtin_amdgcn_s_barrier();
        __builtin_amdgcn_sched_barrier(0);
    }

    // ---- round 6 (even, Aa): stage last pair 7, no A load ----
    STAGE2(7);
    __builtin_amdgcn_sched_barrier(0);
    {
        half8 a[4];
        a[0] = cvt8(Aa[0], Aa[1]); a[1] = cvt8(Aa[2], Aa[3]);
        a[2] = cvt8(Aa[4], Aa[5]); a[3] = cvt8(Aa[6], Aa[7]);
        MFMAS2(6, a);
    }
    asm volatile("s_waitcnt vmcnt(0) lgkmcnt(0)" ::: "memory");     // S(7),A(7) done
    __builtin_amdgcn_s_barrier();
    __builtin_amdgcn_sched_barrier(0);

    // ---- round 7 (odd, Ab) ----
    {
        half8 a[4];
        a[0] = cvt8(Ab[0], Ab[1]); a[1] = cvt8(Ab[2], Ab[3]);
        a[2] = cvt8(Ab[4], Ab[5]); a[3] = cvt8(Ab[6], Ab[7]);
        MFMAS2(7, a);
    }

    // ---- combine K-halves via LDS (overlay on W ring) ----
    __syncthreads();
    {
        float* lgt = (float*)lds + g * LGT_FLOATS;
#pragma unroll
        for (int t = 0; t < 4; ++t)
#pragma unroll
            for (int r = 0; r < 4; ++r)
                lgt[(q * 16 + l4 * 4 + r) * LGT_STRIDE + t * 16 + l15] = acc[t][r];
    }
    __syncthreads();

    // ---------------- entmax-1.5 epilogue ----------------
    // 8 lanes per row, 8 experts per lane; reductions = 3 x shfl_xor {1,2,4}.
    const float* L0 = (const float*)lds;
    const float* L1 = L0 + LGT_FLOATS;
    const int row_local = wave * 8 + (lane >> 3);
    const int eb = (lane & 7) * 8;
    const int base = row_local * LGT_STRIDE + eb;

    float v[8];
    {
        float4 u0 = *(const float4*)(L0 + base);
        float4 u1 = *(const float4*)(L0 + base + 4);
        float4 w0 = *(const float4*)(L1 + base);
        float4 w1 = *(const float4*)(L1 + base + 4);
        float4 c0 = *(const float4*)(bias + eb);
        float4 c1 = *(const float4*)(bias + eb + 4);
        v[0] = u0.x + w0.x + 0.5f * c0.x;
        v[1] = u0.y + w0.y + 0.5f * c0.y;
        v[2] = u0.z + w0.z + 0.5f * c0.z;
        v[3] = u0.w + w0.w + 0.5f * c0.w;
        v[4] = u1.x + w1.x + 0.5f * c1.x;
        v[5] = u1.y + w1.y + 0.5f * c1.y;
        v[6] = u1.z + w1.z + 0.5f * c1.z;
        v[7] = u1.w + w1.w + 0.5f * c1.w;
    }

    float m = v[0];
#pragma unroll
    for (int j = 1; j < 8; ++j) m = fmaxf(m, v[j]);
    m = fmaxf(m, __shfl_xor(m, 1, 64));
    m = fmaxf(m, __shfl_xor(m, 2, 64));
    m = fmaxf(m, __shfl_xor(m, 4, 64));

    float tau_lo = m - 1.0f;
    float tau_hi = m - 0.000244140625f;   // (1/64)^(1/(alpha-1)) = (1/64)^2
    float dm = tau_hi - tau_lo;

    float s0 = 0.f;
#pragma unroll
    for (int j = 0; j < 8; ++j) {
        float d = fmaxf(v[j] - tau_lo, 0.f);
        s0 = fmaf(d, d, s0);
    }
    s0 += __shfl_xor(s0, 1, 64);
    s0 += __shfl_xor(s0, 2, 64);
    s0 += __shfl_xor(s0, 4, 64);
    const float f_lo = s0 - 1.0f;   // fixed for all iterations (as in reference)

    float tau_m = tau_lo, fsum = 1.0f;
#pragma unroll 1
    for (int it = 0; it < 25; ++it) {
        dm *= 0.5f;
        tau_m = tau_lo + dm;
        float s = 0.f;
#pragma unroll
        for (int j = 0; j < 8; ++j) {
            float d = fmaxf(v[j] - tau_m, 0.f);
            s = fmaf(d, d, s);
        }
        s += __shfl_xor(s, 1, 64);
        s += __shfl_xor(s, 2, 64);
        s += __shfl_xor(s, 4, 64);
        if ((s - 1.0f) * f_lo >= 0.0f) tau_lo = tau_m;
        fsum = s;
    }
    // p at last midpoint, renormalized by its own sum (ensure_sum_one)
    float rinv = 1.0f / fsum;
    float4 o0, o1;
    {
        float d;
        d = fmaxf(v[0] - tau_m, 0.f); o0.x = d * d * rinv;
        d = fmaxf(v[1] - tau_m, 0.f); o0.y = d * d * rinv;
        d = fmaxf(v[2] - tau_m, 0.f); o0.z = d * d * rinv;
        d = fmaxf(v[3] - tau_m, 0.f); o0.w = d * d * rinv;
        d = fmaxf(v[4] - tau_m, 0.f); o1.x = d * d * rinv;
        d = fmaxf(v[5] - tau_m, 0.f); o1.y = d * d * rinv;
        d = fmaxf(v[6] - tau_m, 0.f); o1.z = d * d * rinv;
        d = fmaxf(v[7] - tau_m, 0.f); o1.w = d * d * rinv;
    }
    float* op = out + (size_t)(rowbase + row_local) * N_EXP + eb;
    *(float4*)(op)     = o0;
    *(float4*)(op + 4) = o1;
}

// ---------------------------------------------------------------------------
extern "C" void kernel_launch(void* const* d_in, const int* in_sizes, int n_in,
                              void* d_out, int out_size, void* d_ws, size_t ws_size,
                              hipStream_t stream) {
    (void)n_in; (void)out_size; (void)ws_size;
    const float* x  = (const float*)d_in[0];   // [T, 2048]
    const float* W  = (const float*)d_in[1];   // [64, 2048]
    const float* b  = (const float*)d_in[2];   // [64]
    float* out      = (float*)d_out;           // [T, 64]
    uint8_t* wsimg  = (uint8_t*)d_ws;          // 256 KB W fp16 image

    const int T = in_sizes[0] / N_EMBED;       // 32768

    convert_w_kernel<<<dim3(64), dim3(256), 0, stream>>>(W, wsimg);
    router_kernel<<<dim3(T / 64), dim3(512), 0, stream>>>(x, wsimg, b, out);
}

// Round 8
// 59.314 us; speedup vs baseline: 2.9703x; 2.9703x over previous
//
#include <hip/hip_runtime.h>
#include <hip/hip_bf16.h>
#include <stdint.h>

typedef _Float16 half8 __attribute__((ext_vector_type(8)));
typedef float    f32x4 __attribute__((ext_vector_type(4)));

#define N_EMBED   2048
#define N_EXP     64
#define KCHUNK    64
#define NKC       (N_EMBED / KCHUNK)   // 32
#define GCH       16                   // chunks per K-group (K-split 2)
#define TILEB     8192                 // bytes per k-chunk fp16 image
#define LGT_STRIDE 68                  // floats, padded row stride for logit LDS
#define LGT_FLOATS (64 * LGT_STRIDE)   // 4352 floats = 17408 B per region

// ---------------------------------------------------------------------------
// Prelude: W [64][2048] fp32 -> pre-swizzled fp16 image in ws (256 KB).
// Folds the 0.5 = (alpha-1)/temperature scale into W.
// Chunk kc at kc*8192; element (e,dd) at byte ((e*128 + dd*2) ^ ((e&7)<<4)).
// ---------------------------------------------------------------------------
__global__ __launch_bounds__(256) void convert_w_kernel(
        const float* __restrict__ W, uint8_t* __restrict__ wsimg) {
    int tid = blockIdx.x * 256 + threadIdx.x;   // 16384 threads total
    int e   = tid >> 8;                          // expert 0..63
    int d0  = (tid & 255) * 8;                   // 8 consecutive d
    int kc  = d0 >> 6;
    int dd0 = d0 & 63;
    const float* src = W + e * N_EMBED + d0;
    float4 f0 = *(const float4*)(src);
    float4 f1 = *(const float4*)(src + 4);
    float v[8] = {f0.x, f0.y, f0.z, f0.w, f1.x, f1.y, f1.z, f1.w};
    union { _Float16 h[8]; uint4 u; } hv;
#pragma unroll
    for (int j = 0; j < 8; ++j) hv.h[j] = (_Float16)(0.5f * v[j]);
    uint32_t off = (uint32_t)((e * 128 + dd0 * 2) ^ ((e & 7) << 4));
    *(uint4*)(wsimg + (size_t)kc * TILEB + off) = hv.u;
}

// ---------------------------------------------------------------------------
// Main fused kernel, K-split 2, fp16 MFMA, BK=128 (2 chunks per barrier
// round -> 8 rounds; halves per-round convoy cost vs R6's 16 rounds).
//   512 threads = 8 waves = 2 K-groups x 4 row-quads.
//   W: ring-4 LDS = pair-level double buffer (pair p in slots {2p&3,2p+1&3});
//   stage pair p+1 at round-p start. A: ONE register set of 8 named float4,
//   consume (cvt) then reload pair p+1 mid-round. End-of-round wait
//   vmcnt(8) completes the W stage only; A stays in flight. Raw s_barrier.
//   ALL hot-state in individually named registers — nothing array-indexed
//   (R7's float4[8] lambda params went to scratch: 312 MB WRITE_SIZE).
// ---------------------------------------------------------------------------
__device__ __forceinline__ half8 cvt8(const float4& p, const float4& q) {
    half8 h;
    h[0] = (_Float16)p.x; h[1] = (_Float16)p.y;
    h[2] = (_Float16)p.z; h[3] = (_Float16)p.w;
    h[4] = (_Float16)q.x; h[5] = (_Float16)q.y;
    h[6] = (_Float16)q.z; h[7] = (_Float16)q.w;
    return h;
}

__global__ __launch_bounds__(512, 4) void router_kernel(
        const float* __restrict__ x, const uint8_t* __restrict__ img,
        const float* __restrict__ bias, float* __restrict__ out) {
    __shared__ uint8_t lds[65536];   // 2 groups x 4 slots x 8 KB; logits overlay

    const int tid  = threadIdx.x;
    const int wave = tid >> 6;
    const int lane = tid & 63;
    const int l15  = lane & 15;
    const int l4   = lane >> 4;
    const int g    = wave >> 2;        // K-group
    const int q    = wave & 3;         // row quad
    const int rowbase = blockIdx.x * 64;
    const float* xrow = x + (size_t)(rowbase + q * 16 + l15) * N_EMBED
                          + g * (GCH * KCHUNK) + l4 * 8;
    uint8_t* gring = lds + g * (4 * TILEB);

    // LDS byte offsets of B fragments: tile t, k-step s
    uint32_t boff[4][2];
#pragma unroll
    for (int t = 0; t < 4; ++t)
#pragma unroll
        for (int s = 0; s < 2; ++s)
            boff[t][s] = (uint32_t)(((16 * t + l15) * 128 + s * 64 + l4 * 16)
                                    ^ ((l15 & 7) << 4));

    f32x4 acc[4];
#pragma unroll
    for (int t = 0; t < 4; ++t) acc[t] = (f32x4){0.f, 0.f, 0.f, 0.f};

    // Staging: thread-group tg (256 threads) stages its group's chunks.
    const int tg  = tid >> 8;
    const int t8  = tid & 255;
    auto STAGE2 = [&](int p) {   // stage chunks 2p, 2p+1 (4 gload_lds/thread)
#pragma unroll
        for (int c = 0; c < 2; ++c) {
            int kc = 2 * p + c;
            const uint8_t* gsrc = img + (size_t)(tg * GCH + kc) * TILEB;
            uint8_t* dst = lds + tg * (4 * TILEB) + (kc & 3) * TILEB;
#pragma unroll
            for (int j = 0; j < 2; ++j) {
                __builtin_amdgcn_global_load_lds(
                    (const __attribute__((address_space(1))) void*)(gsrc + j * 4096 + t8 * 16),
                    (__attribute__((address_space(3))) void*)(dst + j * 4096 + t8 * 16),
                    16, 0, 0);
            }
        }
    };

    float4 A0, A1, A2, A3, A4, A5, A6, A7;   // one pair set, named regs only
    auto LOADA2 = [&](int p) {               // pair p: 8 x dwordx4
        const float* ap = xrow + 2 * p * KCHUNK;
        A0 = *(const float4*)(ap);
        A1 = *(const float4*)(ap + 4);
        A2 = *(const float4*)(ap + 32);
        A3 = *(const float4*)(ap + 36);
        A4 = *(const float4*)(ap + 64);
        A5 = *(const float4*)(ap + 68);
        A6 = *(const float4*)(ap + 96);
        A7 = *(const float4*)(ap + 100);
    };
    auto MFMAS2 = [&](int p, half8 a0, half8 a1, half8 a2, half8 a3) {
        const uint8_t* lb0 = gring + (size_t)((2 * p) & 3) * TILEB;
        const uint8_t* lb1 = gring + (size_t)((2 * p + 1) & 3) * TILEB;
#pragma unroll
        for (int t = 0; t < 4; ++t) {
            half8 bh = *(const half8*)(lb0 + boff[t][0]);
            acc[t] = __builtin_amdgcn_mfma_f32_16x16x32_f16(a0, bh, acc[t], 0, 0, 0);
        }
#pragma unroll
        for (int t = 0; t < 4; ++t) {
            half8 bh = *(const half8*)(lb0 + boff[t][1]);
            acc[t] = __builtin_amdgcn_mfma_f32_16x16x32_f16(a1, bh, acc[t], 0, 0, 0);
        }
#pragma unroll
        for (int t = 0; t < 4; ++t) {
            half8 bh = *(const half8*)(lb1 + boff[t][0]);
            acc[t] = __builtin_amdgcn_mfma_f32_16x16x32_f16(a2, bh, acc[t], 0, 0, 0);
        }
#pragma unroll
        for (int t = 0; t < 4; ++t) {
            half8 bh = *(const half8*)(lb1 + boff[t][1]);
            acc[t] = __builtin_amdgcn_mfma_f32_16x16x32_f16(a3, bh, acc[t], 0, 0, 0);
        }
    };

    // ---- prologue: stage pair 0; load A pair 0 ----
    STAGE2(0);
    __builtin_amdgcn_sched_barrier(0);
    LOADA2(0);
    __builtin_amdgcn_sched_barrier(0);
    asm volatile("s_waitcnt vmcnt(8)" ::: "memory");   // S(0) done; A(0) in flight
    __builtin_amdgcn_s_barrier();
    __builtin_amdgcn_sched_barrier(0);

    // ---- rounds 0..6 (uniform) ----
#pragma unroll 1
    for (int p = 0; p < 7; ++p) {
        STAGE2(p + 1);
        __builtin_amdgcn_sched_barrier(0);
        {
            // cvt consumes A(p) (compiler inserts the vmcnt for the dep),
            // then the same registers are refilled with pair p+1.
            half8 a0 = cvt8(A0, A1);
            half8 a1 = cvt8(A2, A3);
            half8 a2 = cvt8(A4, A5);
            half8 a3 = cvt8(A6, A7);
            LOADA2(p + 1);
            MFMAS2(p, a0, a1, a2, a3);
        }
        // S(p+1)[4] is older than A(p+1)[8]: vmcnt(8) completes the W stage,
        // leaves the A pair in flight. lgkmcnt(0): my LDS reads of the slots
        // being re-staged next round are done before crossing the barrier.
        asm volatile("s_waitcnt vmcnt(8) lgkmcnt(0)" ::: "memory");
        __builtin_amdgcn_s_barrier();
        __builtin_amdgcn_sched_barrier(0);
    }

    // ---- round 7 (tail): consume A(7), slots {2,3} ----
    {
        half8 a0 = cvt8(A0, A1);
        half8 a1 = cvt8(A2, A3);
        half8 a2 = cvt8(A4, A5);
        half8 a3 = cvt8(A6, A7);
        MFMAS2(7, a0, a1, a2, a3);
    }

    // ---- combine K-halves via LDS (overlay on W ring) ----
    __syncthreads();
    {
        float* lgt = (float*)lds + g * LGT_FLOATS;
#pragma unroll
        for (int t = 0; t < 4; ++t)
#pragma unroll
            for (int r = 0; r < 4; ++r)
                lgt[(q * 16 + l4 * 4 + r) * LGT_STRIDE + t * 16 + l15] = acc[t][r];
    }
    __syncthreads();

    // ---------------- entmax-1.5 epilogue ----------------
    // 8 lanes per row, 8 experts per lane; reductions = 3 x shfl_xor {1,2,4}.
    const float* L0 = (const float*)lds;
    const float* L1 = L0 + LGT_FLOATS;
    const int row_local = wave * 8 + (lane >> 3);
    const int eb = (lane & 7) * 8;
    const int base = row_local * LGT_STRIDE + eb;

    float v0, v1, v2, v3, v4, v5, v6, v7;
    {
        float4 u0 = *(const float4*)(L0 + base);
        float4 u1 = *(const float4*)(L0 + base + 4);
        float4 w0 = *(const float4*)(L1 + base);
        float4 w1 = *(const float4*)(L1 + base + 4);
        float4 c0 = *(const float4*)(bias + eb);
        float4 c1 = *(const float4*)(bias + eb + 4);
        v0 = u0.x + w0.x + 0.5f * c0.x;
        v1 = u0.y + w0.y + 0.5f * c0.y;
        v2 = u0.z + w0.z + 0.5f * c0.z;
        v3 = u0.w + w0.w + 0.5f * c0.w;
        v4 = u1.x + w1.x + 0.5f * c1.x;
        v5 = u1.y + w1.y + 0.5f * c1.y;
        v6 = u1.z + w1.z + 0.5f * c1.z;
        v7 = u1.w + w1.w + 0.5f * c1.w;
    }

    float m = fmaxf(fmaxf(fmaxf(v0, v1), fmaxf(v2, v3)),
                    fmaxf(fmaxf(v4, v5), fmaxf(v6, v7)));
    m = fmaxf(m, __shfl_xor(m, 1, 64));
    m = fmaxf(m, __shfl_xor(m, 2, 64));
    m = fmaxf(m, __shfl_xor(m, 4, 64));

    float tau_lo = m - 1.0f;
    float tau_hi = m - 0.000244140625f;   // (1/64)^(1/(alpha-1)) = (1/64)^2
    float dm = tau_hi - tau_lo;

    float s0;
    {
        float d;
        d = fmaxf(v0 - tau_lo, 0.f); s0 = d * d;
        d = fmaxf(v1 - tau_lo, 0.f); s0 = fmaf(d, d, s0);
        d = fmaxf(v2 - tau_lo, 0.f); s0 = fmaf(d, d, s0);
        d = fmaxf(v3 - tau_lo, 0.f); s0 = fmaf(d, d, s0);
        d = fmaxf(v4 - tau_lo, 0.f); s0 = fmaf(d, d, s0);
        d = fmaxf(v5 - tau_lo, 0.f); s0 = fmaf(d, d, s0);
        d = fmaxf(v6 - tau_lo, 0.f); s0 = fmaf(d, d, s0);
        d = fmaxf(v7 - tau_lo, 0.f); s0 = fmaf(d, d, s0);
    }
    s0 += __shfl_xor(s0, 1, 64);
    s0 += __shfl_xor(s0, 2, 64);
    s0 += __shfl_xor(s0, 4, 64);
    const float f_lo = s0 - 1.0f;   // fixed for all iterations (as in reference)

    float tau_m = tau_lo, fsum = 1.0f;
#pragma unroll 1
    for (int it = 0; it < 25; ++it) {
        dm *= 0.5f;
        tau_m = tau_lo + dm;
        float s, d;
        d = fmaxf(v0 - tau_m, 0.f); s = d * d;
        d = fmaxf(v1 - tau_m, 0.f); s = fmaf(d, d, s);
        d = fmaxf(v2 - tau_m, 0.f); s = fmaf(d, d, s);
        d = fmaxf(v3 - tau_m, 0.f); s = fmaf(d, d, s);
        d = fmaxf(v4 - tau_m, 0.f); s = fmaf(d, d, s);
        d = fmaxf(v5 - tau_m, 0.f); s = fmaf(d, d, s);
        d = fmaxf(v6 - tau_m, 0.f); s = fmaf(d, d, s);
        d = fmaxf(v7 - tau_m, 0.f); s = fmaf(d, d, s);
        s += __shfl_xor(s, 1, 64);
        s += __shfl_xor(s, 2, 64);
        s += __shfl_xor(s, 4, 64);
        if ((s - 1.0f) * f_lo >= 0.0f) tau_lo = tau_m;
        fsum = s;
    }
    // p at last midpoint, renormalized by its own sum (ensure_sum_one)
    float rinv = 1.0f / fsum;
    float4 o0, o1;
    {
        float d;
        d = fmaxf(v0 - tau_m, 0.f); o0.x = d * d * rinv;
        d = fmaxf(v1 - tau_m, 0.f); o0.y = d * d * rinv;
        d = fmaxf(v2 - tau_m, 0.f); o0.z = d * d * rinv;
        d = fmaxf(v3 - tau_m, 0.f); o0.w = d * d * rinv;
        d = fmaxf(v4 - tau_m, 0.f); o1.x = d * d * rinv;
        d = fmaxf(v5 - tau_m, 0.f); o1.y = d * d * rinv;
        d = fmaxf(v6 - tau_m, 0.f); o1.z = d * d * rinv;
        d = fmaxf(v7 - tau_m, 0.f); o1.w = d * d * rinv;
    }
    float* op = out + (size_t)(rowbase + row_local) * N_EXP + eb;
    *(float4*)(op)     = o0;
    *(float4*)(op + 4) = o1;
}

// ---------------------------------------------------------------------------
extern "C" void kernel_launch(void* const* d_in, const int* in_sizes, int n_in,
                              void* d_out, int out_size, void* d_ws, size_t ws_size,
                              hipStream_t stream) {
    (void)n_in; (void)out_size; (void)ws_size;
    const float* x  = (const float*)d_in[0];   // [T, 2048]
    const float* W  = (const float*)d_in[1];   // [64, 2048]
    const float* b  = (const float*)d_in[2];   // [64]
    float* out      = (float*)d_out;           // [T, 64]
    uint8_t* wsimg  = (uint8_t*)d_ws;          // 256 KB W fp16 image

    const int T = in_sizes[0] / N_EMBED;       // 32768

    convert_w_kernel<<<dim3(64), dim3(256), 0, stream>>>(W, wsimg);
    router_kernel<<<dim3(T / 64), dim3(512), 0, stream>>>(x, wsimg, b, out);
}